// Round 4
// baseline (549.811 us; speedup 1.0000x reference)
//
#include <hip/hip_runtime.h>
#include <math.h>

#define SCALEF 0.25f   // 1/sqrt(D=16)

__device__ __forceinline__ unsigned short f2bf(float x) {
  unsigned u = __float_as_uint(x);
  unsigned r = u + 0x7FFFu + ((u >> 16) & 1u);
  return (unsigned short)(r >> 16);
}
__device__ __forceinline__ float bf2f(unsigned short h) {
  return __uint_as_float(((unsigned)h) << 16);
}

// ======================= CSR build =======================
__global__ void k_hist(const int* __restrict__ dst, int* __restrict__ counts, int E) {
  int i = blockIdx.x * 256 + threadIdx.x;
  if (i < E) atomicAdd(&counts[dst[i]], 1);
}

__global__ __launch_bounds__(1024) void k_scan1(const int* __restrict__ counts,
                                                int* __restrict__ excl,
                                                int* __restrict__ bsums, int n) {
  __shared__ int sd[1024];
  int t = threadIdx.x;
  int i = blockIdx.x * 1024 + t;
  int v = (i < n) ? counts[i] : 0;
  sd[t] = v;
  __syncthreads();
  for (int off = 1; off < 1024; off <<= 1) {
    int x = (t >= off) ? sd[t - off] : 0;
    __syncthreads();
    sd[t] += x;
    __syncthreads();
  }
  if (i < n) excl[i] = sd[t] - v;
  if (t == 1023) bsums[blockIdx.x] = sd[1023];
}

__global__ void k_scan2(int* bsums, int nb) {
  if (threadIdx.x == 0 && blockIdx.x == 0) {
    int run = 0;
    for (int i = 0; i < nb; ++i) { int v = bsums[i]; bsums[i] = run; run += v; }
  }
}

__global__ __launch_bounds__(1024) void k_scan3(int* __restrict__ rowptr, int* __restrict__ cursor,
                                                const int* __restrict__ bsums, int n, int Etot) {
  int i = blockIdx.x * 1024 + threadIdx.x;
  if (i < n) { int v = rowptr[i] + bsums[blockIdx.x]; rowptr[i] = v; cursor[i] = v; }
  if (i == 0) rowptr[n] = Etot;
}

__global__ void k_scatter(const int* __restrict__ dst, int* __restrict__ cursor,
                          int* __restrict__ colidx, int E) {
  int i = blockIdx.x * 256 + threadIdx.x;
  if (i < E) { int pos = atomicAdd(&cursor[dst[i]], 1); colidx[pos] = i; }
}

// permute esrc + edge_attr into CSR order; edge_attr -> bf16 (streamed in attn)
__global__ void k_perm(const int* __restrict__ colidx, const int* __restrict__ esrc,
                       const float* __restrict__ EA, int* __restrict__ esrcp,
                       unsigned short* __restrict__ EAp, int E) {
  int r = blockIdx.x * 256 + threadIdx.x;
  if (r >= E) return;
  const int eid = colidx[r];
  esrcp[r] = esrc[eid];
  const float4* s4 = (const float4*)(EA + ((size_t)eid << 4));
  float4 a = s4[0], b = s4[1], c = s4[2], d = s4[3];
  union { unsigned short us[16]; uint4 u4[2]; } o;
  o.us[0] = f2bf(a.x); o.us[1] = f2bf(a.y); o.us[2] = f2bf(a.z); o.us[3] = f2bf(a.w);
  o.us[4] = f2bf(b.x); o.us[5] = f2bf(b.y); o.us[6] = f2bf(b.z); o.us[7] = f2bf(b.w);
  o.us[8] = f2bf(c.x); o.us[9] = f2bf(c.y); o.us[10] = f2bf(c.z); o.us[11] = f2bf(c.w);
  o.us[12] = f2bf(d.x); o.us[13] = f2bf(d.y); o.us[14] = f2bf(d.z); o.us[15] = f2bf(d.w);
  uint4* d4 = (uint4*)(EAp + ((size_t)r << 4));
  d4[0] = o.u4[0]; d4[1] = o.u4[1];
}

// ======================= node linear: Q,K,V,Skip =======================
// Register-blocked LDS GEMM; Q,S stored f32; K,V stored bf16 for the gather phase.
#define LB 64
#define XPAD 68
__global__ __launch_bounds__(256) void k_lin(const float* __restrict__ X,
    const float* __restrict__ Wq, const float* __restrict__ bq,
    const float* __restrict__ Wk, const float* __restrict__ bk,
    const float* __restrict__ Wv, const float* __restrict__ bv,
    const float* __restrict__ Ws, const float* __restrict__ bs,
    float* __restrict__ Q, unsigned short* __restrict__ Kb,
    unsigned short* __restrict__ Vb, float* __restrict__ S,
    int n) {
  __shared__ float Xl[64][XPAD];     // 17.4 KB
  __shared__ float Wl[2][64][64];    // 32 KB
  const int t = threadIdx.x;
  const int lane = t & 63;
  const int wv = t >> 6;
  const int n0 = blockIdx.x * LB;

  // stage X transposed: Xl[k][row] = X[n0+row][k]
  {
    const int row = t >> 2;
    const int node = n0 + row;
    const bool ok = node < n;
    const float4* src = (const float4*)(X + (size_t)node * 64);
    #pragma unroll
    for (int cc = 0; cc < 4; ++cc) {
      const int chunk = (t & 3) + cc * 4;
      float4 v = ok ? src[chunk] : make_float4(0.f, 0.f, 0.f, 0.f);
      const int k0 = chunk * 4;
      Xl[k0 + 0][row] = v.x;
      Xl[k0 + 1][row] = v.y;
      Xl[k0 + 2][row] = v.z;
      Xl[k0 + 3][row] = v.w;
    }
  }

  const float* Wm[4] = {Wq, Wk, Wv, Ws};
  const float* bm[4] = {bq, bk, bv, bs};

  const int rg = lane >> 2;
  const int c0 = wv * 16 + (lane & 3) * 4;

  for (int ph = 0; ph < 2; ++ph) {
    if (ph) __syncthreads();
    {
      const float4* w0 = (const float4*)Wm[ph * 2 + 0];
      const float4* w1 = (const float4*)Wm[ph * 2 + 1];
      float4* d0 = (float4*)&Wl[0][0][0];
      float4* d1 = (float4*)&Wl[1][0][0];
      for (int i = t; i < 1024; i += 256) { d0[i] = w0[i]; d1[i] = w1[i]; }
    }
    __syncthreads();

    #pragma unroll
    for (int m = 0; m < 2; ++m) {
      const int mat = ph * 2 + m;
      float a[4][4];
      #pragma unroll
      for (int i = 0; i < 4; ++i)
        #pragma unroll
        for (int j = 0; j < 4; ++j) a[i][j] = 0.f;

      #pragma unroll 8
      for (int k = 0; k < 64; ++k) {
        const float4 xv = *(const float4*)&Xl[k][rg * 4];
        const float4 wv4 = *(const float4*)&Wl[m][k][c0];
        const float xs[4] = {xv.x, xv.y, xv.z, xv.w};
        #pragma unroll
        for (int i = 0; i < 4; ++i) {
          a[i][0] += xs[i] * wv4.x;
          a[i][1] += xs[i] * wv4.y;
          a[i][2] += xs[i] * wv4.z;
          a[i][3] += xs[i] * wv4.w;
        }
      }

      const float4 bias = *(const float4*)(bm[mat] + c0);
      if (mat == 1 || mat == 2) {
        unsigned short* O = (mat == 1) ? Kb : Vb;
        #pragma unroll
        for (int i = 0; i < 4; ++i) {
          const int node = n0 + rg * 4 + i;
          if (node < n) {
            ushort4 r;
            r.x = f2bf(a[i][0] + bias.x);
            r.y = f2bf(a[i][1] + bias.y);
            r.z = f2bf(a[i][2] + bias.z);
            r.w = f2bf(a[i][3] + bias.w);
            *(ushort4*)(O + (size_t)node * 64 + c0) = r;
          }
        }
      } else {
        float* O = (mat == 0) ? Q : S;
        #pragma unroll
        for (int i = 0; i < 4; ++i) {
          const int node = n0 + rg * 4 + i;
          if (node < n) {
            float4 r;
            r.x = a[i][0] + bias.x;
            r.y = a[i][1] + bias.y;
            r.z = a[i][2] + bias.z;
            r.w = a[i][3] + bias.w;
            *(float4*)(O + (size_t)node * 64 + c0) = r;
          }
        }
      }
    }
  }
}

// ======================= fused edge/attention kernel =======================
// One wave per dst node, block = 2 waves. bf16 K/V gathers, CSR-streamed
// esrcp/EAp, 3-stage software pipeline (named regs, no runtime indexing).
#define LOADST(KK, VV, E0, E1, jj) do {                                   \
    int jc_ = (jj) < mc ? (jj) : mc - 1;                                  \
    int sn_ = __builtin_amdgcn_readlane(snv, jc_);                        \
    KK = Kb[(size_t)sn_ * 64 + lane];                                     \
    VV = Vb[(size_t)sn_ * 64 + lane];                                     \
    const uint4* ep_ = (const uint4*)(EAp + ((size_t)(c0 + jc_) << 4));   \
    E0 = ep_[0]; E1 = ep_[1];                                             \
  } while (0)

#define COMPUTE(KK, VV, E0, E1, jj) do {                                  \
    if ((jj) < mc) {                                                      \
      float e =  __uint_as_float(E0.x << 16)          * WeL[0][lane];     \
      e += __uint_as_float(E0.x & 0xFFFF0000u)        * WeL[1][lane];     \
      e += __uint_as_float(E0.y << 16)                * WeL[2][lane];     \
      e += __uint_as_float(E0.y & 0xFFFF0000u)        * WeL[3][lane];     \
      e += __uint_as_float(E0.z << 16)                * WeL[4][lane];     \
      e += __uint_as_float(E0.z & 0xFFFF0000u)        * WeL[5][lane];     \
      e += __uint_as_float(E0.w << 16)                * WeL[6][lane];     \
      e += __uint_as_float(E0.w & 0xFFFF0000u)        * WeL[7][lane];     \
      e += __uint_as_float(E1.x << 16)                * WeL[8][lane];     \
      e += __uint_as_float(E1.x & 0xFFFF0000u)        * WeL[9][lane];     \
      e += __uint_as_float(E1.y << 16)                * WeL[10][lane];    \
      e += __uint_as_float(E1.y & 0xFFFF0000u)        * WeL[11][lane];    \
      e += __uint_as_float(E1.z << 16)                * WeL[12][lane];    \
      e += __uint_as_float(E1.z & 0xFFFF0000u)        * WeL[13][lane];    \
      e += __uint_as_float(E1.w << 16)                * WeL[14][lane];    \
      e += __uint_as_float(E1.w & 0xFFFF0000u)        * WeL[15][lane];    \
      const float ke = bf2f(KK) + e;                                      \
      const float ve = bf2f(VV) + e;                                      \
      float prod = qv * ke;                                               \
      prod += __shfl_xor(prod, 1, 64);                                    \
      prod += __shfl_xor(prod, 2, 64);                                    \
      prod += __shfl_xor(prod, 4, 64);                                    \
      prod += __shfl_xor(prod, 8, 64);                                    \
      const float mn = fmaxf(m, prod);                                    \
      const float fold = __expf(m - mn);                                  \
      const float p = __expf(prod - mn);                                  \
      ssum = ssum * fold + p;                                             \
      acc  = acc  * fold + p * ve;                                        \
      m = mn;                                                             \
    }                                                                     \
  } while (0)

__global__ __launch_bounds__(128, 4) void k_attn(
    const float* __restrict__ Q, const unsigned short* __restrict__ Kb,
    const unsigned short* __restrict__ Vb,
    const float* __restrict__ S, const unsigned short* __restrict__ EAp,
    const int* __restrict__ esrcp, const int* __restrict__ rowptr,
    const float* __restrict__ We, const float* __restrict__ Wb,
    float* __restrict__ Hout, int n) {
  __shared__ float WeL[16][64];   // 4 KiB
  const int t = threadIdx.x;
  for (int i = t; i < 16 * 64; i += 128) WeL[i >> 6][i & 63] = We[i];
  __syncthreads();

  const int lane = t & 63;
  const float wb0 = Wb[lane], wb1 = Wb[64 + lane], wb2 = Wb[128 + lane];
  const int node = blockIdx.x * 2 + (t >> 6);
  if (node >= n) return;

  const float qv = Q[(size_t)node * 64 + lane] * SCALEF;
  const float sk = S[(size_t)node * 64 + lane];
  const int r0 = rowptr[node], r1 = rowptr[node + 1];

  float m = -1e30f, ssum = 0.f, acc = 0.f;

  for (int c0 = r0; c0 < r1; c0 += 64) {
    const int mc = min(64, r1 - c0);
    int snv = 0;
    if (lane < mc) snv = esrcp[c0 + lane];

    unsigned short kA, vA, kB, vB, kC, vC;
    uint4 eA0, eA1, eB0, eB1, eC0, eC1;
    LOADST(kA, vA, eA0, eA1, 0);
    LOADST(kB, vB, eB0, eB1, 1);
    LOADST(kC, vC, eC0, eC1, 2);

    for (int j = 0; j < mc; j += 3) {
      COMPUTE(kA, vA, eA0, eA1, j);
      LOADST(kA, vA, eA0, eA1, j + 3);
      COMPUTE(kB, vB, eB0, eB1, j + 1);
      LOADST(kB, vB, eB0, eB1, j + 4);
      COMPUTE(kC, vC, eC0, eC1, j + 2);
      LOADST(kC, vC, eC0, eC1, j + 5);
    }
  }

  const float a = acc / (ssum + 1e-16f);
  float contrib = a * wb0 + sk * wb1 + (a - sk) * wb2;
  #pragma unroll
  for (int off = 1; off < 64; off <<= 1) contrib += __shfl_xor(contrib, off, 64);
  const float beta = 1.f / (1.f + __expf(-contrib));
  const float o = beta * sk + (1.f - beta) * a;
  Hout[(size_t)node * 64 + lane] = fmaxf(o, 0.f);
}

// ======================= pooling: one block per graph, batch sorted =======================
__global__ __launch_bounds__(256) void k_pool(const float* __restrict__ Hf,
    const int* __restrict__ batch,
    float* __restrict__ gmax, float* __restrict__ gmean, int n) {
  const int g = blockIdx.x;
  const int lane = threadIdx.x & 63;
  const int w = threadIdx.x >> 6;

  int a = 0, b = n;
  while (a < b) { int mid = (a + b) >> 1; if (batch[mid] < g) a = mid + 1; else b = mid; }
  const int lo = a;
  b = n;
  while (a < b) { int mid = (a + b) >> 1; if (batch[mid] < g + 1) a = mid + 1; else b = mid; }
  const int hi = a;

  float vmax = -1e30f, vsum = 0.f;
  for (int i = lo + w; i < hi; i += 4) {
    const float v = Hf[(size_t)i * 64 + lane];
    vmax = fmaxf(vmax, v);
    vsum += v;
  }
  __shared__ float smax[4][64], ssum[4][64];
  smax[w][lane] = vmax;
  ssum[w][lane] = vsum;
  __syncthreads();
  if (w == 0) {
    const float mx = fmaxf(fmaxf(smax[0][lane], smax[1][lane]),
                           fmaxf(smax[2][lane], smax[3][lane]));
    const float sm = ssum[0][lane] + ssum[1][lane] + ssum[2][lane] + ssum[3][lane];
    const int cnt = hi - lo;
    gmax[g * 64 + lane]  = (cnt > 0) ? mx : 0.f;
    gmean[g * 64 + lane] = sm / fmaxf((float)cnt, 1.f);
  }
}

// ======================= final MLP =======================
__global__ __launch_bounds__(256) void k_mlp(const float* __restrict__ gmax,
    const float* __restrict__ gmean,
    const float* __restrict__ Wlin, const float* __restrict__ blin,
    const float* __restrict__ Wout, const float* __restrict__ bout,
    float* __restrict__ out, int G) {
  __shared__ float cat[128];
  __shared__ float red[4];
  const int g = blockIdx.x;
  const int t = threadIdx.x;
  if (t < 64) cat[t] = gmax[g * 64 + t];
  else if (t < 128) cat[t] = gmean[g * 64 + (t - 64)];
  __syncthreads();
  float acc = blin[t];
  for (int j = 0; j < 128; ++j) acc += cat[j] * Wlin[j * 256 + t];
  float p = acc * Wout[t];
  #pragma unroll
  for (int off = 1; off < 64; off <<= 1) p += __shfl_xor(p, off, 64);
  if ((t & 63) == 0) red[t >> 6] = p;
  __syncthreads();
  if (t == 0) {
    const float z = red[0] + red[1] + red[2] + red[3] + bout[0];
    out[g] = 1.f / (1.f + __expf(-z));
  }
}

// ======================= launcher =======================
extern "C" void kernel_launch(void* const* d_in, const int* in_sizes, int n_in,
                              void* d_out, int out_size, void* d_ws, size_t ws_size,
                              hipStream_t stream) {
  const float* x     = (const float*)d_in[0];
  const float* ea    = (const float*)d_in[1];
  const int*   eidx  = (const int*)d_in[2];
  const int*   batch = (const int*)d_in[3];
  const float *Wq0 = (const float*)d_in[4],  *bq0 = (const float*)d_in[5];
  const float *Wk0 = (const float*)d_in[6],  *bk0 = (const float*)d_in[7];
  const float *Wv0 = (const float*)d_in[8],  *bv0 = (const float*)d_in[9];
  const float *We0 = (const float*)d_in[10];
  const float *Ws0 = (const float*)d_in[11], *bs0 = (const float*)d_in[12];
  const float *Wb0 = (const float*)d_in[13];
  const float *Wq  = (const float*)d_in[14], *bq  = (const float*)d_in[15];
  const float *Wk  = (const float*)d_in[16], *bk  = (const float*)d_in[17];
  const float *Wv  = (const float*)d_in[18], *bv  = (const float*)d_in[19];
  const float *We  = (const float*)d_in[20];
  const float *Ws  = (const float*)d_in[21], *bs  = (const float*)d_in[22];
  const float *Wb  = (const float*)d_in[23];
  const float *Wlin = (const float*)d_in[24], *blin = (const float*)d_in[25];
  const float *Wout = (const float*)d_in[26], *bout = (const float*)d_in[27];

  const int N = in_sizes[0] / 64;
  const int E = in_sizes[2] / 2;
  const int G = out_size;
  const int* esrc = eidx;
  const int* edst = eidx + E;

  // ---- workspace carve ----
  char* wsp = (char*)d_ws;
  auto alloc = [&](size_t bytes) -> void* {
    void* p = (void*)wsp;
    wsp += (bytes + 255) & ~(size_t)255;
    return p;
  };
  float* Qb = (float*)alloc((size_t)N * 64 * 4);
  float* Sb = (float*)alloc((size_t)N * 64 * 4);
  float* Hb = (float*)alloc((size_t)N * 64 * 4);
  unsigned short* Kb = (unsigned short*)alloc((size_t)N * 64 * 2);
  unsigned short* Vb = (unsigned short*)alloc((size_t)N * 64 * 2);
  int* counts  = (int*)alloc((size_t)N * 4);
  int* rowptr  = (int*)alloc((size_t)(N + 1) * 4);
  int* cursor  = (int*)alloc((size_t)N * 4);
  int* colidx  = (int*)alloc((size_t)E * 4);
  int* bsums   = (int*)alloc(1024 * 4);
  int* esrcp   = (int*)alloc((size_t)E * 4);
  unsigned short* EAp = (unsigned short*)alloc((size_t)E * 16 * 2);
  float* gmaxf  = (float*)alloc((size_t)G * 64 * 4);
  float* gmeanf = (float*)alloc((size_t)G * 64 * 4);

  // ---- CSR build (edges grouped by dst) ----
  const int gridE = (E + 255) / 256;
  const int NB1 = (N + 1023) / 1024;
  hipMemsetAsync(counts, 0, (size_t)N * 4, stream);
  k_hist<<<gridE, 256, 0, stream>>>(edst, counts, E);
  k_scan1<<<NB1, 1024, 0, stream>>>(counts, rowptr, bsums, N);
  k_scan2<<<1, 64, 0, stream>>>(bsums, NB1);
  k_scan3<<<NB1, 1024, 0, stream>>>(rowptr, cursor, bsums, N, E);
  k_scatter<<<gridE, 256, 0, stream>>>(edst, cursor, colidx, E);
  k_perm<<<gridE, 256, 0, stream>>>(colidx, esrc, ea, esrcp, EAp, E);

  // ---- 4 TransformerConv layers ----
  const int gridLin  = (N + LB - 1) / LB;
  const int gridAttn = (N + 1) / 2;
  for (int l = 0; l < 4; ++l) {
    const float *wq, *bq_, *wk, *bk_, *wv, *bv_, *we_, *ws_, *bs_, *wb_;
    const float* hin;
    if (l == 0) {
      hin = x;
      wq = Wq0; bq_ = bq0; wk = Wk0; bk_ = bk0; wv = Wv0; bv_ = bv0;
      we_ = We0; ws_ = Ws0; bs_ = bs0; wb_ = Wb0;
    } else {
      const int li = l - 1;
      hin = Hb;
      wq = Wq + li * 4096; bq_ = bq + li * 64;
      wk = Wk + li * 4096; bk_ = bk + li * 64;
      wv = Wv + li * 4096; bv_ = bv + li * 64;
      we_ = We + li * 1024;
      ws_ = Ws + li * 4096; bs_ = bs + li * 64;
      wb_ = Wb + li * 192;
    }
    k_lin<<<gridLin, 256, 0, stream>>>(hin, wq, bq_, wk, bk_, wv, bv_, ws_, bs_,
                                       Qb, Kb, Vb, Sb, N);
    k_attn<<<gridAttn, 128, 0, stream>>>(Qb, Kb, Vb, Sb, EAp, esrcp, rowptr,
                                         we_, wb_, Hb, N);
  }

  // ---- pooling: one block per graph ----
  k_pool<<<G, 256, 0, stream>>>(Hb, batch, gmaxf, gmeanf, N);

  // ---- MLP head ----
  k_mlp<<<G, 256, 0, stream>>>(gmaxf, gmeanf, Wlin, blin, Wout, bout,
                               (float*)d_out, G);
}